// Round 1
// 1766.047 us; speedup vs baseline: 1.0127x; 1.0127x over previous
//
#include <hip/hip_runtime.h>

#define N 8192
#define EPS 1e-8f

// ---- bf16 helpers (manual, positive finite values only) ----
__device__ __forceinline__ unsigned short f2bf(float f) {
    // round-to-nearest-even
    unsigned int u = __float_as_uint(f);
    unsigned int rounding = 0x7FFFu + ((u >> 16) & 1u);
    return (unsigned short)((u + rounding) >> 16);
}
__device__ __forceinline__ float bflo(unsigned int w) { return __uint_as_float(w << 16); }
__device__ __forceinline__ float bfhi(unsigned int w) { return __uint_as_float(w & 0xffff0000u); }
__device__ __forceinline__ unsigned int pack2(unsigned short lo, unsigned short hi) {
    return (unsigned int)lo | ((unsigned int)hi << 16);
}

// dot of 8 packed bf16 (uint4) with 8 floats (two float4)
__device__ __forceinline__ float dot8(uint4 kv, float4 xa, float4 xb) {
    float a = 0.f;
    a = fmaf(bflo(kv.x), xa.x, a);
    a = fmaf(bfhi(kv.x), xa.y, a);
    a = fmaf(bflo(kv.y), xa.z, a);
    a = fmaf(bfhi(kv.y), xa.w, a);
    a = fmaf(bflo(kv.z), xb.x, a);
    a = fmaf(bfhi(kv.z), xb.y, a);
    a = fmaf(bflo(kv.w), xb.z, a);
    a = fmaf(bfhi(kv.w), xb.w, a);
    return a;
}

// ---- init v = 1/N ----
__global__ __launch_bounds__(256) void init_v_kernel(float* __restrict__ v) {
    int i = blockIdx.x * 256 + threadIdx.x;
    if (i < N) v[i] = 1.0f / (float)N;
}

// ---- build K (bf16, row-major) from s, m. Pure elementwise, 8 elems/thread ----
__global__ __launch_bounds__(256) void build_K_kernel(
    const float* __restrict__ s, const float* __restrict__ m,
    unsigned short* __restrict__ K) {
    const size_t base = ((size_t)blockIdx.x * 256 + threadIdx.x) * 8;
    const float4 sa = *(const float4*)(s + base);
    const float4 sb = *(const float4*)(s + base + 4);
    const float4 ma = *(const float4*)(m + base);
    const float4 mb = *(const float4*)(m + base + 4);
    const unsigned short k0 = f2bf(__expf(sa.x) * ma.x);
    const unsigned short k1 = f2bf(__expf(sa.y) * ma.y);
    const unsigned short k2 = f2bf(__expf(sa.z) * ma.z);
    const unsigned short k3 = f2bf(__expf(sa.w) * ma.w);
    const unsigned short k4 = f2bf(__expf(sb.x) * mb.x);
    const unsigned short k5 = f2bf(__expf(sb.y) * mb.y);
    const unsigned short k6 = f2bf(__expf(sb.z) * mb.z);
    const unsigned short k7 = f2bf(__expf(sb.w) * mb.w);
    uint4 pk;
    pk.x = pack2(k0, k1);
    pk.y = pack2(k2, k3);
    pk.z = pack2(k4, k5);
    pk.w = pack2(k6, k7);
    *(uint4*)(K + base) = pk;
}

// ---- fused matvec + reciprocal: out[i] = 1 / (eps + sum_j K[i][j] * x[j]) ----
// K row-major 8192x8192 bf16. 8 rows per block, 256 threads.
#define RPB 8
__global__ __launch_bounds__(256) void matvec_recip_kernel(
    const unsigned short* __restrict__ M, const float* __restrict__ x,
    float* __restrict__ out) {
    const int rowBase = blockIdx.x * RPB;
    const int tid = threadIdx.x;

    float acc[RPB];
    #pragma unroll
    for (int r = 0; r < RPB; ++r) acc[r] = 0.f;

    #pragma unroll
    for (int sweep = 0; sweep < 4; ++sweep) {
        const int col = sweep * 2048 + tid * 8;
        const float4 xa = *(const float4*)(x + col);
        const float4 xb = *(const float4*)(x + col + 4);
        #pragma unroll
        for (int r = 0; r < RPB; ++r) {
            const uint4 kv = *(const uint4*)(M + (size_t)(rowBase + r) * N + col);
            acc[r] += dot8(kv, xa, xb);
        }
    }

    // reduce across the block: wave shuffle then LDS
    __shared__ float wred[RPB][4];
    const int lane = tid & 63;
    const int wave = tid >> 6;
    #pragma unroll
    for (int r = 0; r < RPB; ++r) {
        float a = acc[r];
        #pragma unroll
        for (int off = 32; off > 0; off >>= 1) a += __shfl_down(a, off, 64);
        if (lane == 0) wred[r][wave] = a;
    }
    __syncthreads();
    if (tid < RPB) {
        const float ssum = wred[tid][0] + wred[tid][1] + wred[tid][2] + wred[tid][3];
        out[rowBase + tid] = 1.0f / (ssum + EPS);
    }
}

// ---- transpose matvec stage 1: partial[chunk][j] = sum_{i in chunk} K[i][j]*u[i] ----
// Reads row-major K directly (no KT materialization). Tile: TROWS x TCOLS per block.
// Thread layout: rg = tid>>5 (row group 0..7), cl = tid&31 (2 cols each -> 64 cols).
// Half-wave reads 128 B contiguous per row: coalesced at cache-line granularity.
#define TCOLS 64
#define TROWS 1024
__global__ __launch_bounds__(256) void matvecT_partial_kernel(
    const unsigned short* __restrict__ K, const float* __restrict__ u,
    float* __restrict__ partial) {
    const int colBase = blockIdx.x * TCOLS;
    const int rowBase = blockIdx.y * TROWS;
    const int tid = threadIdx.x;

    // preload the u chunk for this row range (4 KB)
    __shared__ __align__(16) float su[TROWS];
    *(float4*)(su + tid * 4) = *(const float4*)(u + rowBase + tid * 4);
    __syncthreads();

    const int rg = tid >> 5;   // 0..7
    const int cl = tid & 31;   // 0..31 -> cols colBase + 2*cl, +1
    float acc0 = 0.f, acc1 = 0.f;
    const unsigned short* Kp = K + (size_t)(rowBase + rg) * N + colBase + cl * 2;
    #pragma unroll 8
    for (int it = 0; it < TROWS / 8; ++it) {
        const unsigned int w = *(const unsigned int*)(Kp + (size_t)(it * 8) * N);
        const float uv = su[it * 8 + rg];
        acc0 = fmaf(bflo(w), uv, acc0);
        acc1 = fmaf(bfhi(w), uv, acc1);
    }

    // reduce the 8 row-groups per column
    __shared__ __align__(8) float wred[8][TCOLS];
    *(float2*)&wred[rg][cl * 2] = make_float2(acc0, acc1);
    __syncthreads();
    if (tid < TCOLS) {
        float ssum = 0.f;
        #pragma unroll
        for (int g = 0; g < 8; ++g) ssum += wred[g][tid];
        partial[(size_t)blockIdx.y * N + colBase + tid] = ssum;
    }
}

// ---- transpose matvec stage 2: v[j] = 1/(eps + sum_chunk partial[chunk][j]) ----
__global__ __launch_bounds__(256) void reduceT_recip_kernel(
    const float* __restrict__ partial, float* __restrict__ v) {
    const int col = blockIdx.x * 256 + threadIdx.x;
    float ssum = 0.f;
    #pragma unroll
    for (int c = 0; c < N / TROWS; ++c) ssum += partial[(size_t)c * N + col];
    v[col] = 1.0f / (ssum + EPS);
}

// ---- final: out[i][j] = u[i] * exp(s[i][j]) * m[i][j] * v[j] (fp32 exact K) ----
__global__ __launch_bounds__(256) void final_kernel(
    const float* __restrict__ s, const float* __restrict__ m,
    const float* __restrict__ u, const float* __restrict__ v,
    float* __restrict__ out) {
    const int row = blockIdx.x;
    const float ur = u[row];
    const int tid = threadIdx.x;
    #pragma unroll
    for (int sweep = 0; sweep < 8; ++sweep) {
        const int col = sweep * 1024 + tid * 4;
        const size_t idx = (size_t)row * N + col;
        const float4 s4 = *(const float4*)(s + idx);
        const float4 m4 = *(const float4*)(m + idx);
        const float4 v4 = *(const float4*)(v + col);
        float4 o;
        o.x = ur * __expf(s4.x) * m4.x * v4.x;
        o.y = ur * __expf(s4.y) * m4.y * v4.y;
        o.z = ur * __expf(s4.z) * m4.z * v4.z;
        o.w = ur * __expf(s4.w) * m4.w * v4.w;
        *(float4*)(out + idx) = o;
    }
}

extern "C" void kernel_launch(void* const* d_in, const int* in_sizes, int n_in,
                              void* d_out, int out_size, void* d_ws, size_t ws_size,
                              hipStream_t stream) {
    const float* eta = (const float*)d_in[0];
    const float* s = eta;                       // eta_result[0]: scores
    const float* m = eta + (size_t)N * N;       // eta_result[1]: mask
    float* out = (float*)d_out;

    // workspace layout: K bf16 (128 MiB) | partial (8*N f32) | u (32 KiB) | v (32 KiB)
    unsigned short* K = (unsigned short*)d_ws;
    float* partial = (float*)(K + (size_t)N * N);
    float* u = partial + (size_t)(N / TROWS) * N;
    float* v = u + N;

    init_v_kernel<<<N / 256, 256, 0, stream>>>(v);
    build_K_kernel<<<(int)(((size_t)N * N) / 2048), 256, 0, stream>>>(s, m, K);
    for (int it = 0; it < 20; ++it) {
        // u = 1/(K v + eps)
        matvec_recip_kernel<<<N / RPB, 256, 0, stream>>>(K, v, u);
        // v = 1/(K^T u + eps), computed from row-major K (K stays L3-resident)
        matvecT_partial_kernel<<<dim3(N / TCOLS, N / TROWS), 256, 0, stream>>>(K, u, partial);
        reduceT_recip_kernel<<<N / 256, 256, 0, stream>>>(partial, v);
    }
    final_kernel<<<N, 256, 0, stream>>>(s, m, u, v, out);
}